// Round 5
// baseline (508.324 us; speedup 1.0000x reference)
//
#include <hip/hip_runtime.h>

#define DD 64
#define LATENT 32
#define OUTD 64
#define CAP 64         // binned-edge capacity per node; counts ~ Poisson(10), P(>=64) ~ 1e-35

typedef float vfloat4 __attribute__((ext_vector_type(4)));

// ---------------------------------------------------------------------------
// 1) Bin + g1 in one dispatch. Blocks [0, edgeBlocks) bin edges (4/lane via
//    int4); tail blocks compute g1[b][j] = b1[j] + global_attr[b].W1[128+k][j].
//    counts[] doubles as the mean divisor.
// ---------------------------------------------------------------------------
__global__ __launch_bounds__(256) void bin_g1_kernel(
    const int*   __restrict__ recv, int* __restrict__ counts,
    int*         __restrict__ slots, int nEdges, int edgeBlocks,
    const float* __restrict__ global_attr,  // [64*64]
    const float* __restrict__ W1,           // [192*32]
    const float* __restrict__ b1,           // [32]
    float*       __restrict__ g1,           // [64*32]
    int nBatch)
{
    const int bid = blockIdx.x;
    if (bid >= edgeBlocks) {                 // ---- g1 tail blocks ----
        int t = (bid - edgeBlocks) * 256 + threadIdx.x;
        int b = t >> 5;
        int j = t & 31;
        if (b >= nBatch) return;
        float acc = b1[j];
        const float* g = global_attr + (size_t)b * DD;
        const float* w = W1 + 128 * LATENT + j;
        for (int k = 0; k < DD; ++k)
            acc = fmaf(g[k], w[k * LATENT], acc);
        g1[b * LATENT + j] = acc;
        return;
    }
    // ---- edge binning ----
    int t = bid * 256 + threadIdx.x;
    int e0 = t * 4;
    if (e0 + 3 < nEdges) {
        int4 r4 = *(const int4*)(recv + e0);
        int rank;
        rank = atomicAdd(&counts[r4.x], 1); if (rank < CAP) slots[((size_t)r4.x << 6) + rank] = e0;
        rank = atomicAdd(&counts[r4.y], 1); if (rank < CAP) slots[((size_t)r4.y << 6) + rank] = e0 + 1;
        rank = atomicAdd(&counts[r4.z], 1); if (rank < CAP) slots[((size_t)r4.z << 6) + rank] = e0 + 2;
        rank = atomicAdd(&counts[r4.w], 1); if (rank < CAP) slots[((size_t)r4.w << 6) + rank] = e0 + 3;
    } else {
        for (int e = e0; e < nEdges; ++e) {
            int r = recv[e];
            int rank = atomicAdd(&counts[r], 1);
            if (rank < CAP) slots[((size_t)r << 6) + rank] = e;
        }
    }
}

// ---------------------------------------------------------------------------
// 2) Fused gather + MLP. One wave owns 64 nodes; no barriers anywhere
//    (wave-synchronous LDS use, in-order DS pipe).
//    Gather: per node, only the first 16 slot ids are read (one broadcast
//    64B line into lanes 0-15, prefetched one node ahead); nodes with
//    cnt>16 (~2%) reload 16 ids per extra chunk (wave-uniform branch).
//    16 rows per chunk via 4 independent exec-masked nontemporal dwordx4
//    row loads (4KB in flight/wave); 4-group partial sums reduced with 2
//    shfl_xor rounds; mean written straight into the LDS slab.
//    MLP: node_attr reg-staged with NT loads BEFORE the mean segment so the
//    global traffic overlaps segB's FMA block (slab still holds means at
//    that point, so registers are the only overlap vehicle); then segB
//    (W1 rows [64,128)), slab flip to node_attr, segA (W1 rows [0,64)),
//    ReLU, layer 2, transposed spill -> coalesced NT stores.
// ---------------------------------------------------------------------------
__global__ __launch_bounds__(128) void fused_kernel(
    const float* __restrict__ edge_attr,   // [nEdges*64]
    const int*   __restrict__ slots,       // [nNodes*CAP]
    const int*   __restrict__ counts,      // [nNodes]
    const float* __restrict__ node_attr,   // [nNodes*64]
    const int*   __restrict__ ng_index,    // [nNodes]
    const float* __restrict__ W1,          // [192*32] row-major [k][j]
    const float* __restrict__ W2,          // [32*64]
    const float* __restrict__ b2,          // [64]
    const float* __restrict__ g1,          // [64*32]
    float*       __restrict__ out,         // [nNodes*64]
    int nNodes)
{
    __shared__ float slab[2][64 * 65];     // 33.3 KB -> 4 blocks/CU (LDS-limited)

    const int wave = threadIdx.x >> 6;
    const int lane = threadIdx.x & 63;
    const int base = blockIdx.x * 128 + wave * 64;
    if (base >= nNodes) return;            // wave-uniform early out
    const int nv = min(64, nNodes - base);
    float* S = slab[wave];
    const int g  = lane >> 4;              // row-group within the wave
    const int s  = lane & 15;              // 16B chunk within a row
    const int l16 = lane & 15;             // id-slot within the 64B id line

    // ---- h init = g1[ng_index[n]]  (8 KB table, cache-resident) ----
    float h[LATENT];
    {
        const int n = base + (lane < nv ? lane : 0);
        const int gb = ng_index[n];
        const vfloat4* gp = (const vfloat4*)(g1 + gb * LATENT);
#pragma unroll
        for (int q = 0; q < 8; ++q) {
            vfloat4 gv = gp[q];
            h[4*q+0] = gv.x; h[4*q+1] = gv.y;
            h[4*q+2] = gv.z; h[4*q+3] = gv.w;
        }
    }

    // ---- gather phase: 64 node-means into the slab ----
    int cnt_n  = counts[base];                                  // prefetch node 0
    int myid_n = slots[((size_t)base << 6) + l16];              // first 16 ids (64B)
    for (int r = 0; r < nv; ++r) {
        const int cnt = cnt_n;
        int myid = myid_n;
        if (r + 1 < nv) {                                       // prefetch node r+1
            cnt_n  = counts[base + r + 1];
            myid_n = slots[((size_t)(base + r + 1) << 6) + l16];
        }
        const int lim = min(cnt, CAP);

        vfloat4 acc = {0.f, 0.f, 0.f, 0.f};
        for (int i = 0; i < lim; i += 16) {
            if (i > 0)                                          // rare (cnt>16): next 16 ids
                myid = slots[((size_t)(base + r) << 6) + i + l16];
            int ia  = min(i + g,      lim - 1) - i;             // in [0,16)
            int ib  = min(i + 4 + g,  lim - 1) - i;
            int ic  = min(i + 8 + g,  lim - 1) - i;
            int id_ = min(i + 12 + g, lim - 1) - i;
            int eA = __shfl(myid, ia, 64);
            int eB = __shfl(myid, ib, 64);
            int eC = __shfl(myid, ic, 64);
            int eD = __shfl(myid, id_, 64);
            vfloat4 a = {0.f,0.f,0.f,0.f}, b = a, c = a, d = a;
            if (i + g < lim)
                a = __builtin_nontemporal_load(((const vfloat4*)(edge_attr + (size_t)eA * DD)) + s);
            if (i + 4 + g < lim)
                b = __builtin_nontemporal_load(((const vfloat4*)(edge_attr + (size_t)eB * DD)) + s);
            if (i + 8 + g < lim)
                c = __builtin_nontemporal_load(((const vfloat4*)(edge_attr + (size_t)eC * DD)) + s);
            if (i + 12 + g < lim)
                d = __builtin_nontemporal_load(((const vfloat4*)(edge_attr + (size_t)eD * DD)) + s);
            acc += a; acc += b; acc += c; acc += d;
        }
        // sum the 4 groups: xor-16 then xor-32
        acc.x += __shfl_xor(acc.x, 16, 64);
        acc.y += __shfl_xor(acc.y, 16, 64);
        acc.z += __shfl_xor(acc.z, 16, 64);
        acc.w += __shfl_xor(acc.w, 16, 64);
        acc.x += __shfl_xor(acc.x, 32, 64);
        acc.y += __shfl_xor(acc.y, 32, 64);
        acc.z += __shfl_xor(acc.z, 32, 64);
        acc.w += __shfl_xor(acc.w, 32, 64);

        if (g == 0) {
            float inv = 1.0f / (float)max(cnt, 1);
            S[r * 65 + 4*s + 0] = acc.x * inv;
            S[r * 65 + 4*s + 1] = acc.y * inv;
            S[r * 65 + 4*s + 2] = acc.z * inv;
            S[r * 65 + 4*s + 3] = acc.w * inv;
        }
    }

    // ---- issue node_attr reg-stage loads (overlap with segB compute) ----
    float na[64];
#pragma unroll
    for (int r = 0; r < 64; ++r)
        if (r < nv)
            na[r] = __builtin_nontemporal_load(node_attr + (size_t)(base + r) * DD + lane);

    // ---- segment B: mean rows (in slab) through W1 rows [64,128) ----
    {
        const float* w = W1 + DD * LATENT;
#pragma unroll 8
        for (int k = 0; k < DD; ++k) {
            float x = S[lane * 65 + k];
            const float* wr = w + k * LATENT;
#pragma unroll
            for (int j = 0; j < LATENT; ++j)
                h[j] = fmaf(x, wr[j], h[j]);
        }
    }

    // ---- flip slab to node_attr, consume through W1 rows [0,64) ----
#pragma unroll
    for (int r = 0; r < 64; ++r)
        if (r < nv)
            S[r * 65 + lane] = na[r];
    {
        const float* w = W1;
#pragma unroll 8
        for (int k = 0; k < DD; ++k) {
            float x = S[lane * 65 + k];
            const float* wr = w + k * LATENT;
#pragma unroll
            for (int j = 0; j < LATENT; ++j)
                h[j] = fmaf(x, wr[j], h[j]);
        }
    }

    // ReLU
#pragma unroll
    for (int j = 0; j < LATENT; ++j) h[j] = fmaxf(h[j], 0.0f);

    // ---- layer 2: two chunks of 32 outputs, spill transposed into slab ----
#pragma unroll
    for (int c = 0; c < 2; ++c) {
        float o[32];
#pragma unroll
        for (int t = 0; t < 32; ++t) o[t] = b2[c * 32 + t];
        for (int j = 0; j < LATENT; ++j) {
            const float hj = h[j];
            const float* wr = W2 + j * OUTD + c * 32;
#pragma unroll
            for (int t = 0; t < 32; ++t) o[t] = fmaf(hj, wr[t], o[t]);
        }
#pragma unroll
        for (int t = 0; t < 32; ++t) S[lane * 65 + c * 32 + t] = o[t];
    }

    // ---- coalesced NT store (lane=feature) ----
#pragma unroll 8
    for (int r = 0; r < nv; ++r)
        __builtin_nontemporal_store(S[r * 65 + lane],
                                    out + (size_t)(base + r) * DD + lane);
}

extern "C" void kernel_launch(void* const* d_in, const int* in_sizes, int n_in,
                              void* d_out, int out_size, void* d_ws, size_t ws_size,
                              hipStream_t stream)
{
    const float* node_attr   = (const float*)d_in[0];
    const float* edge_attr   = (const float*)d_in[1];
    const float* global_attr = (const float*)d_in[2];
    const float* W1          = (const float*)d_in[3];
    const float* b1          = (const float*)d_in[4];
    const float* W2          = (const float*)d_in[5];
    const float* b2          = (const float*)d_in[6];
    const int*   recv        = (const int*)d_in[7];
    const int*   ng_index    = (const int*)d_in[8];
    float*       out         = (float*)d_out;

    const int nNodes = in_sizes[0] / DD;
    const int nEdges = in_sizes[1] / DD;
    const int nBatch = in_sizes[2] / DD;

    // ws layout: counts[nNodes] | slots[nNodes*CAP] | g1[64*32]f   (~26 MB)
    int*   counts = (int*)d_ws;
    int*   slots  = counts + nNodes;
    float* g1     = (float*)(slots + (size_t)nNodes * CAP);

    hipMemsetAsync(counts, 0, (size_t)nNodes * sizeof(int), stream);

    const int edgeBlocks = (nEdges + 1023) / 1024;
    const int g1Blocks   = (nBatch * LATENT + 255) / 256;
    bin_g1_kernel<<<edgeBlocks + g1Blocks, 256, 0, stream>>>(
        recv, counts, slots, nEdges, edgeBlocks,
        global_attr, W1, b1, g1, nBatch);

    fused_kernel<<<(nNodes + 127) / 128, 128, 0, stream>>>(
        edge_attr, slots, counts, node_attr, ng_index, W1, W2, b2, g1, out, nNodes);
}

// Round 6
// 480.572 us; speedup vs baseline: 1.0577x; 1.0577x over previous
//
#include <hip/hip_runtime.h>

#define DD 64
#define LATENT 32
#define OUTD 64
#define CAP 64         // binned-edge capacity per node; counts ~ Poisson(10), P(>=64) ~ 1e-35

typedef float vfloat4 __attribute__((ext_vector_type(4)));

// ---------------------------------------------------------------------------
// 1) Bin + g1 in one dispatch (the ONE retained R4 change: saves a launch).
//    Blocks [0, edgeBlocks) bin edges (4/lane via int4); tail blocks compute
//    g1[b][j] = b1[j] + global_attr[b].W1[128+k][j]. counts[] doubles as the
//    mean divisor.
// ---------------------------------------------------------------------------
__global__ __launch_bounds__(256) void bin_g1_kernel(
    const int*   __restrict__ recv, int* __restrict__ counts,
    int*         __restrict__ slots, int nEdges, int edgeBlocks,
    const float* __restrict__ global_attr,  // [64*64]
    const float* __restrict__ W1,           // [192*32]
    const float* __restrict__ b1,           // [32]
    float*       __restrict__ g1,           // [64*32]
    int nBatch)
{
    const int bid = blockIdx.x;
    if (bid >= edgeBlocks) {                 // ---- g1 tail blocks ----
        int t = (bid - edgeBlocks) * 256 + threadIdx.x;
        int b = t >> 5;
        int j = t & 31;
        if (b >= nBatch) return;
        float acc = b1[j];
        const float* g = global_attr + (size_t)b * DD;
        const float* w = W1 + 128 * LATENT + j;
        for (int k = 0; k < DD; ++k)
            acc = fmaf(g[k], w[k * LATENT], acc);
        g1[b * LATENT + j] = acc;
        return;
    }
    // ---- edge binning ----
    int t = bid * 256 + threadIdx.x;
    int e0 = t * 4;
    if (e0 + 3 < nEdges) {
        int4 r4 = *(const int4*)(recv + e0);
        int rank;
        rank = atomicAdd(&counts[r4.x], 1); if (rank < CAP) slots[((size_t)r4.x << 6) + rank] = e0;
        rank = atomicAdd(&counts[r4.y], 1); if (rank < CAP) slots[((size_t)r4.y << 6) + rank] = e0 + 1;
        rank = atomicAdd(&counts[r4.z], 1); if (rank < CAP) slots[((size_t)r4.z << 6) + rank] = e0 + 2;
        rank = atomicAdd(&counts[r4.w], 1); if (rank < CAP) slots[((size_t)r4.w << 6) + rank] = e0 + 3;
    } else {
        for (int e = e0; e < nEdges; ++e) {
            int r = recv[e];
            int rank = atomicAdd(&counts[r], 1);
            if (rank < CAP) slots[((size_t)r << 6) + rank] = e;
        }
    }
}

// ---------------------------------------------------------------------------
// 2) Fused gather + MLP — exact R3 structure (best measured: 485 us).
//    One wave owns 64 nodes; no barriers anywhere (wave-synchronous LDS).
//    Gather: slot ids via ONE unconditional coalesced 256B read prefetched
//    one node ahead (no cnt->ids dependent chain); 16 rows per inner iter
//    via 4 independent exec-masked nontemporal dwordx4 row loads (4KB in
//    flight/wave); 4-group partial sums reduced with 2 shfl_xor rounds;
//    mean written straight into the LDS slab (no global round-trip).
//    MLP: segB (W1 rows [64,128)) from slab, restage node_attr direct
//    global->LDS (NO register staging — R4's na[64] reg-stage regressed
//    23us, VGPR pressure), segA (W1 rows [0,64)), ReLU, layer 2,
//    transposed spill -> coalesced plain stores.
// ---------------------------------------------------------------------------
__global__ __launch_bounds__(128) void fused_kernel(
    const float* __restrict__ edge_attr,   // [nEdges*64]
    const int*   __restrict__ slots,       // [nNodes*CAP]
    const int*   __restrict__ counts,      // [nNodes]
    const float* __restrict__ node_attr,   // [nNodes*64]
    const int*   __restrict__ ng_index,    // [nNodes]
    const float* __restrict__ W1,          // [192*32] row-major [k][j]
    const float* __restrict__ W2,          // [32*64]
    const float* __restrict__ b2,          // [64]
    const float* __restrict__ g1,          // [64*32]
    float*       __restrict__ out,         // [nNodes*64]
    int nNodes)
{
    __shared__ float slab[2][64 * 65];     // 33.3 KB -> 4 blocks/CU

    const int wave = threadIdx.x >> 6;
    const int lane = threadIdx.x & 63;
    const int base = blockIdx.x * 128 + wave * 64;
    if (base >= nNodes) return;            // wave-uniform early out
    const int nv = min(64, nNodes - base);
    float* S = slab[wave];
    const int g = lane >> 4;               // row-group within the wave
    const int s = lane & 15;               // 16B chunk within a row

    // ---- h init = g1[ng_index[n]]  (8 KB table, cache-resident) ----
    float h[LATENT];
    {
        const int n = base + (lane < nv ? lane : 0);
        const int gb = ng_index[n];
        const vfloat4* gp = (const vfloat4*)(g1 + gb * LATENT);
#pragma unroll
        for (int q = 0; q < 8; ++q) {
            vfloat4 gv = gp[q];
            h[4*q+0] = gv.x; h[4*q+1] = gv.y;
            h[4*q+2] = gv.z; h[4*q+3] = gv.w;
        }
    }

    // ---- gather phase: 64 node-means into the slab ----
    int cnt_n  = counts[base];                                  // prefetch node 0
    int myid_n = slots[((size_t)base << 6) + lane];
    for (int r = 0; r < nv; ++r) {
        const int cnt  = cnt_n;
        const int myid = myid_n;
        if (r + 1 < nv) {                                       // prefetch node r+1
            cnt_n  = counts[base + r + 1];
            myid_n = slots[((size_t)(base + r + 1) << 6) + lane];
        }
        const int lim = min(cnt, CAP);

        vfloat4 acc = {0.f, 0.f, 0.f, 0.f};
        for (int i = 0; i < lim; i += 16) {
            int ia  = min(i + g,      lim - 1);
            int ib  = min(i + 4 + g,  lim - 1);
            int ic  = min(i + 8 + g,  lim - 1);
            int id_ = min(i + 12 + g, lim - 1);
            int eA = __shfl(myid, ia, 64);
            int eB = __shfl(myid, ib, 64);
            int eC = __shfl(myid, ic, 64);
            int eD = __shfl(myid, id_, 64);
            vfloat4 a = {0.f,0.f,0.f,0.f}, b = a, c = a, d = a;
            if (i + g < lim)
                a = __builtin_nontemporal_load(((const vfloat4*)(edge_attr + (size_t)eA * DD)) + s);
            if (i + 4 + g < lim)
                b = __builtin_nontemporal_load(((const vfloat4*)(edge_attr + (size_t)eB * DD)) + s);
            if (i + 8 + g < lim)
                c = __builtin_nontemporal_load(((const vfloat4*)(edge_attr + (size_t)eC * DD)) + s);
            if (i + 12 + g < lim)
                d = __builtin_nontemporal_load(((const vfloat4*)(edge_attr + (size_t)eD * DD)) + s);
            acc += a; acc += b; acc += c; acc += d;
        }
        // sum the 4 groups: xor-16 then xor-32
        acc.x += __shfl_xor(acc.x, 16, 64);
        acc.y += __shfl_xor(acc.y, 16, 64);
        acc.z += __shfl_xor(acc.z, 16, 64);
        acc.w += __shfl_xor(acc.w, 16, 64);
        acc.x += __shfl_xor(acc.x, 32, 64);
        acc.y += __shfl_xor(acc.y, 32, 64);
        acc.z += __shfl_xor(acc.z, 32, 64);
        acc.w += __shfl_xor(acc.w, 32, 64);

        if (g == 0) {
            float inv = 1.0f / (float)max(cnt, 1);
            S[r * 65 + 4*s + 0] = acc.x * inv;
            S[r * 65 + 4*s + 1] = acc.y * inv;
            S[r * 65 + 4*s + 2] = acc.z * inv;
            S[r * 65 + 4*s + 3] = acc.w * inv;
        }
    }

    // ---- segment B: mean rows (already in slab) through W1 rows [64,128) ----
    {
        const float* w = W1 + DD * LATENT;
#pragma unroll 8
        for (int k = 0; k < DD; ++k) {
            float x = S[lane * 65 + k];
            const float* wr = w + k * LATENT;
#pragma unroll
            for (int j = 0; j < LATENT; ++j)
                h[j] = fmaf(x, wr[j], h[j]);
        }
    }

    // ---- segment A: node_attr through W1 rows [0,64) ----
#pragma unroll 8
    for (int r = 0; r < nv; ++r)
        S[r * 65 + lane] = node_attr[(size_t)(base + r) * DD + lane];
    {
        const float* w = W1;
#pragma unroll 8
        for (int k = 0; k < DD; ++k) {
            float x = S[lane * 65 + k];
            const float* wr = w + k * LATENT;
#pragma unroll
            for (int j = 0; j < LATENT; ++j)
                h[j] = fmaf(x, wr[j], h[j]);
        }
    }

    // ReLU
#pragma unroll
    for (int j = 0; j < LATENT; ++j) h[j] = fmaxf(h[j], 0.0f);

    // ---- layer 2: two chunks of 32 outputs, spill transposed into slab ----
#pragma unroll
    for (int c = 0; c < 2; ++c) {
        float o[32];
#pragma unroll
        for (int t = 0; t < 32; ++t) o[t] = b2[c * 32 + t];
        for (int j = 0; j < LATENT; ++j) {
            const float hj = h[j];
            const float* wr = W2 + j * OUTD + c * 32;
#pragma unroll
            for (int t = 0; t < 32; ++t) o[t] = fmaf(hj, wr[t], o[t]);
        }
#pragma unroll
        for (int t = 0; t < 32; ++t) S[lane * 65 + c * 32 + t] = o[t];
    }

    // ---- coalesced store (lane=feature) ----
#pragma unroll 8
    for (int r = 0; r < nv; ++r)
        out[(size_t)(base + r) * DD + lane] = S[r * 65 + lane];
}

extern "C" void kernel_launch(void* const* d_in, const int* in_sizes, int n_in,
                              void* d_out, int out_size, void* d_ws, size_t ws_size,
                              hipStream_t stream)
{
    const float* node_attr   = (const float*)d_in[0];
    const float* edge_attr   = (const float*)d_in[1];
    const float* global_attr = (const float*)d_in[2];
    const float* W1          = (const float*)d_in[3];
    const float* b1          = (const float*)d_in[4];
    const float* W2          = (const float*)d_in[5];
    const float* b2          = (const float*)d_in[6];
    const int*   recv        = (const int*)d_in[7];
    const int*   ng_index    = (const int*)d_in[8];
    float*       out         = (float*)d_out;

    const int nNodes = in_sizes[0] / DD;
    const int nEdges = in_sizes[1] / DD;
    const int nBatch = in_sizes[2] / DD;

    // ws layout: counts[nNodes] | slots[nNodes*CAP] | g1[64*32]f   (~26 MB)
    int*   counts = (int*)d_ws;
    int*   slots  = counts + nNodes;
    float* g1     = (float*)(slots + (size_t)nNodes * CAP);

    hipMemsetAsync(counts, 0, (size_t)nNodes * sizeof(int), stream);

    const int edgeBlocks = (nEdges + 1023) / 1024;
    const int g1Blocks   = (nBatch * LATENT + 255) / 256;
    bin_g1_kernel<<<edgeBlocks + g1Blocks, 256, 0, stream>>>(
        recv, counts, slots, nEdges, edgeBlocks,
        global_attr, W1, b1, g1, nBatch);

    fused_kernel<<<(nNodes + 127) / 128, 128, 0, stream>>>(
        edge_attr, slots, counts, node_attr, ng_index, W1, W2, b2, g1, out, nNodes);
}